// Round 13
// baseline (31.444 us; speedup 1.0000x reference)
//
#include <hip/hip_runtime.h>
#include <math.h>

// Problem constants (fixed by setup_inputs)
#define BATCH 4
#define NPTS  2048
#define CHAN  32
#define CONVF 332.07156

#define THREADS 256
#define NBLOCKS 1024
#define TOTTHREADS (NBLOCKS * THREADS)      // 262144 = 512 rows x 512 quads
#define QPB (NPTS / 4)                       // 512 quads per row
#define ROWSPAN (TOTTHREADS / QPB)           // 512 rows per sweep
#define NITER (BATCH * NPTS / ROWSPAN)       // 16 iterations per thread
#define NQUADS (BATCH * NPTS / 4)            // 8192, pkT plane stride

typedef float f4v __attribute__((ext_vector_type(4)));

// --- Kernel A: pack i-side structs + quad-transposed j-side planes --------
// pkI[row] = {x,y,z,q},{Px,Py,Pz,ai}     (i-side, wave-uniform reads)
// pkT[s][quad] = plane s of quad's 4 pts (j-side, coalesced; aj in plane 7)
__global__ void pack_points(const float* __restrict__ X,
                            const float* __restrict__ embs,
                            const float* __restrict__ qs,
                            const float* __restrict__ Ps,
                            const float* __restrict__ sfw,
                            float4* __restrict__ pkI,  // (B*N*2)
                            float* __restrict__ pkT) { // (8*NQUADS*4)
    int idx = blockIdx.x * blockDim.x + threadIdx.x;
    if (idx >= BATCH * NPTS) return;
    int n = idx & (NPTS - 1);
    const float* e = embs + (size_t)idx * CHAN;
    float sj = 0.f, si = 0.f;
#pragma unroll
    for (int k = 0; k < CHAN; ++k) {
        float ev = e[k];
        sj = fmaf(ev, sfw[k], sj);
        si = fmaf(ev, sfw[CHAN + k], si);
    }
    float xv = X[idx * 3 + 0], yv = X[idx * 3 + 1], zv = X[idx * 3 + 2];
    float qv = qs[n];
    float Px = Ps[n * 3 + 0], Py = Ps[n * 3 + 1], Pz = Ps[n * 3 + 2];

    float4 a, bb;
    a.x = xv; a.y = yv; a.z = zv; a.w = qv;
    bb.x = Px; bb.y = Py; bb.z = Pz; bb.w = si;   // i-side carries ai dot
    pkI[idx * 2 + 0] = a;
    pkI[idx * 2 + 1] = bb;

    int q = idx >> 2, t = idx & 3;
    pkT[(0 * NQUADS + q) * 4 + t] = xv;
    pkT[(1 * NQUADS + q) * 4 + t] = yv;
    pkT[(2 * NQUADS + q) * 4 + t] = zv;
    pkT[(3 * NQUADS + q) * 4 + t] = qv;
    pkT[(4 * NQUADS + q) * 4 + t] = Px;
    pkT[(5 * NQUADS + q) * 4 + t] = Py;
    pkT[(6 * NQUADS + q) * 4 + t] = Pz;
    pkT[(7 * NQUADS + q) * 4 + t] = sj;            // j-side carries aj dot
}

// --- Kernel B: jq-constant grid-stride stream, 4-slot rolling prefetch ----
__global__ __launch_bounds__(THREADS, 2) void pair_energy(
    const float4* __restrict__ pkI,  // (B*N*2)  i-side
    const f4v* __restrict__ pkT4,    // (8*NQUADS) j-side planes
    const f4v* __restrict__ mask4,   // (B*N*N/4)
    const float* __restrict__ sfw,   // (2C+1,)
    double* __restrict__ partials)   // (NBLOCKS,)
{
    const float wd = sfw[2 * CHAN];
    const int tid = threadIdx.x;
    const int T = blockIdx.x * THREADS + tid;
    const int jq = T & (QPB - 1);        // fixed quad column, 0..511
    const int rowstart = T >> 9;         // 0..511

    f4v ms[4];
    f4v vx, vy, vz, vq, vpx, vpy, vpz, vaj;
    double acc = 0.0;

    // ---- prologue: 4 mask slots in flight + j-side for batch 0 ----
#pragma unroll
    for (int g = 0; g < 4; ++g)
        ms[g] = __builtin_nontemporal_load(
            &mask4[(size_t)(rowstart + g * ROWSPAN) * QPB + jq]);
    vx  = pkT4[0 * NQUADS + jq];
    vy  = pkT4[1 * NQUADS + jq];
    vz  = pkT4[2 * NQUADS + jq];
    vq  = pkT4[3 * NQUADS + jq];
    vpx = pkT4[4 * NQUADS + jq];
    vpy = pkT4[5 * NQUADS + jq];
    vpz = pkT4[6 * NQUADS + jq];
    vaj = pkT4[7 * NQUADS + jq];

    // ---- steady-state stream: compute slot g, refill with g+4 ----
#pragma unroll
    for (int g = 0; g < NITER; ++g) {
        if ((g & 3) == 0 && g > 0) {
            // batch changed (b = g>>2): reload j-side planes
            const int qidx = (g >> 2) * QPB + jq;
            vx  = pkT4[0 * NQUADS + qidx];
            vy  = pkT4[1 * NQUADS + qidx];
            vz  = pkT4[2 * NQUADS + qidx];
            vq  = pkT4[3 * NQUADS + qidx];
            vpx = pkT4[4 * NQUADS + qidx];
            vpy = pkT4[5 * NQUADS + qidx];
            vpz = pkT4[6 * NQUADS + qidx];
            vaj = pkT4[7 * NQUADS + qidx];
        }
        const int row = rowstart + g * ROWSPAN;
        f4v mr = ms[g & 3];                       // capture current slot
        if (g + 4 < NITER)                        // refill: keep stream alive
            ms[g & 3] = __builtin_nontemporal_load(
                &mask4[(size_t)(row + 4 * ROWSPAN) * QPB + jq]);
        // i-side (wave-uniform, L1 broadcast)
        float4 a = pkI[row * 2 + 0];
        float4 p = pkI[row * 2 + 1];              // w = ai dot
        // pin: prefetch + i-side loads issue before compute
        __builtin_amdgcn_sched_barrier(0);

        float cP = 1e-6f * (p.x + p.y + p.z);     // eps-dot, row-constant
        float es = 0.f;
#pragma unroll
        for (int t = 0; t < 4; ++t) {
            float dx = vx[t] - a.x;
            float dy = vy[t] - a.y;
            float dz = vz[t] - a.z;
            float d2 = fmaf(dx, dx, fmaf(dy, dy, fmaf(dz, dz, 3e-6f)));
            float invD = __builtin_amdgcn_rsqf(d2);   // ~1/(D+1e-6), ~1/|V+eps|
            float OqP = fmaf(dx, p.x, fmaf(dy, p.y, fmaf(dz, p.z, cP)));
            float OPP = fmaf(p.x, vpx[t], fmaf(p.y, vpy[t], p.z * vpz[t]));
            float Q12 = a.w * vq[t];
            float sf  = fmaf(invD, wd, p.w + vaj[t]);
            float invD2 = invD * invD;
            float invD4 = invD2 * invD2;
            float invD5 = invD4 * invD;
            float invD6 = invD4 * invD2;
            float E = fmaf(Q12 * invD, sf,
                      fmaf(OqP, invD5, OPP * invD6));
            es = fmaf(mr[t], E, es);
        }
        acc += (double)es;
    }

    // ---- wave shuffle reduce + 4-entry LDS combine ----
#pragma unroll
    for (int s = 32; s > 0; s >>= 1)
        acc += __shfl_xor(acc, s, 64);

    __shared__ double wsum[THREADS / 64];
    const int lane = tid & 63;
    const int wid  = tid >> 6;
    if (lane == 0) wsum[wid] = acc;
    __syncthreads();
    if (tid == 0)
        partials[blockIdx.x] = wsum[0] + wsum[1] + wsum[2] + wsum[3];
}

// --- Kernel C: final reduction + scale + NaN guard ------------------------
__global__ void finalize(const double* __restrict__ partials, int n,
                         float* __restrict__ out) {
    __shared__ double sdata[256];
    double a = 0.0;
    for (int i = threadIdx.x; i < n; i += 256) a += partials[i];
    sdata[threadIdx.x] = a;
    __syncthreads();
#pragma unroll
    for (int s = 128; s > 0; s >>= 1) {
        if (threadIdx.x < s) sdata[threadIdx.x] += sdata[threadIdx.x + s];
        __syncthreads();
    }
    if (threadIdx.x == 0) {
        double tot = sdata[0] * (double)CONVF * 0.5;
        float f = (float)tot;
        out[0] = isnan(f) ? 1e-6f : f;
    }
}

extern "C" void kernel_launch(void* const* d_in, const int* in_sizes, int n_in,
                              void* d_out, int out_size, void* d_ws, size_t ws_size,
                              hipStream_t stream) {
    const float* X    = (const float*)d_in[0];
    const float* embs = (const float*)d_in[1];
    const float* qs   = (const float*)d_in[2];
    const float* Ps   = (const float*)d_in[3];
    const float* mask = (const float*)d_in[4];
    const float* sfw  = (const float*)d_in[5];
    float* out = (float*)d_out;

    // workspace: [ partials double[NBLOCKS] | pkI float4[B*N*2] | pkT float[8*NQUADS*4] ]
    double* partials = (double*)d_ws;
    float4* pkI = (float4*)(partials + NBLOCKS);
    float*  pkT = (float*)(pkI + BATCH * NPTS * 2);

    pack_points<<<(BATCH * NPTS + 255) / 256, 256, 0, stream>>>(X, embs, qs, Ps, sfw,
                                                                pkI, pkT);
    pair_energy<<<NBLOCKS, THREADS, 0, stream>>>(pkI, (const f4v*)pkT,
                                                 (const f4v*)mask, sfw, partials);
    finalize<<<1, 256, 0, stream>>>(partials, NBLOCKS, out);
}

// Round 14
// 26.129 us; speedup vs baseline: 1.2034x; 1.2034x over previous
//
#include <hip/hip_runtime.h>
#include <math.h>

// Problem constants (fixed by setup_inputs)
#define BATCH 4
#define NPTS  2048
#define CHAN  32
#define CONVF 332.07156

#define ROWS 8
#define THREADS 512                       // one full row of quads per thread set
#define NBLOCKS (BATCH * NPTS / ROWS)     // 1024 blocks, 8 consecutive rows each
#define NQUADS (BATCH * NPTS / 4)         // 8192, pkT plane stride
#define QPB (NPTS / 4)                    // 512 quads per row

typedef float f4v __attribute__((ext_vector_type(4)));

// --- Kernel A: pack i-side structs + quad-transposed j-side planes --------
// pkI[row] = {x,y,z,q},{Px,Py,Pz,ai}     (i-side, wave-uniform reads)
// pkT[s][quad] = plane s of quad's 4 pts (j-side, coalesced; aj in plane 7)
__global__ void pack_points(const float* __restrict__ X,
                            const float* __restrict__ embs,
                            const float* __restrict__ qs,
                            const float* __restrict__ Ps,
                            const float* __restrict__ sfw,
                            float4* __restrict__ pkI,  // (B*N*2)
                            float* __restrict__ pkT) { // (8*NQUADS*4)
    int idx = blockIdx.x * blockDim.x + threadIdx.x;
    if (idx >= BATCH * NPTS) return;
    int n = idx & (NPTS - 1);
    const float* e = embs + (size_t)idx * CHAN;
    float sj = 0.f, si = 0.f;
#pragma unroll
    for (int k = 0; k < CHAN; ++k) {
        float ev = e[k];
        sj = fmaf(ev, sfw[k], sj);
        si = fmaf(ev, sfw[CHAN + k], si);
    }
    float xv = X[idx * 3 + 0], yv = X[idx * 3 + 1], zv = X[idx * 3 + 2];
    float qv = qs[n];
    float Px = Ps[n * 3 + 0], Py = Ps[n * 3 + 1], Pz = Ps[n * 3 + 2];

    float4 a, bb;
    a.x = xv; a.y = yv; a.z = zv; a.w = qv;
    bb.x = Px; bb.y = Py; bb.z = Pz; bb.w = si;   // i-side carries ai dot
    pkI[idx * 2 + 0] = a;
    pkI[idx * 2 + 1] = bb;

    int q = idx >> 2, t = idx & 3;
    pkT[(0 * NQUADS + q) * 4 + t] = xv;
    pkT[(1 * NQUADS + q) * 4 + t] = yv;
    pkT[(2 * NQUADS + q) * 4 + t] = zv;
    pkT[(3 * NQUADS + q) * 4 + t] = qv;
    pkT[(4 * NQUADS + q) * 4 + t] = Px;
    pkT[(5 * NQUADS + q) * 4 + t] = Py;
    pkT[(6 * NQUADS + q) * 4 + t] = Pz;
    pkT[(7 * NQUADS + q) * 4 + t] = sj;            // j-side carries aj dot
}

// --- Kernel B: 8 consecutive full rows per block -> contiguous 64KB span --
__global__ __launch_bounds__(THREADS, 1) void pair_energy(
    const float4* __restrict__ pkI,  // (B*N*2)  i-side
    const f4v* __restrict__ pkT4,    // (8*NQUADS) j-side planes
    const f4v* __restrict__ mask4,   // (B*N*N/4)
    const float* __restrict__ sfw,   // (2C+1,)
    double* __restrict__ partials)   // (NBLOCKS,)
{
    const float wd = sfw[2 * CHAN];
    const int tid = threadIdx.x;
    const int r0 = blockIdx.x * ROWS;      // 8 consecutive global rows
    const int b  = r0 >> 11;
    const int jq = tid;                    // quad column, 0..511 (full row)
    const int qidx = b * QPB + jq;

    // ---- j-side planes FIRST (consumed first; L2-resident) ----
    f4v vx  = pkT4[0 * NQUADS + qidx];
    f4v vy  = pkT4[1 * NQUADS + qidx];
    f4v vz  = pkT4[2 * NQUADS + qidx];
    f4v vq  = pkT4[3 * NQUADS + qidx];
    f4v vpx = pkT4[4 * NQUADS + qidx];
    f4v vpy = pkT4[5 * NQUADS + qidx];
    f4v vpz = pkT4[6 * NQUADS + qidx];
    f4v vaj = pkT4[7 * NQUADS + qidx];

    // ---- mask: 8 rows; block aggregate = one contiguous 64KB span ----
    f4v m[ROWS];
#pragma unroll
    for (int r = 0; r < ROWS; ++r)
        m[r] = __builtin_nontemporal_load(
            &mask4[(size_t)(r0 + r) * QPB + jq]);

    // Pin: all 16 loads outstanding before compute (counted vmcnt per row).
    __builtin_amdgcn_sched_barrier(0);

    // ---- compute: 8 rows x 4 pairs ----
    double acc = 0.0;
#pragma unroll
    for (int r = 0; r < ROWS; ++r) {
        const int row = r0 + r;
        // i-side: block-uniform -> scalar loads
        float4 a = pkI[row * 2 + 0];
        float4 p = pkI[row * 2 + 1];          // w = ai dot
        float cP = 1e-6f * (p.x + p.y + p.z); // eps-dot, row-constant
        float es = 0.f;
#pragma unroll
        for (int t = 0; t < 4; ++t) {
            float dx = vx[t] - a.x;
            float dy = vy[t] - a.y;
            float dz = vz[t] - a.z;
            float d2 = fmaf(dx, dx, fmaf(dy, dy, fmaf(dz, dz, 3e-6f)));
            float invD = __builtin_amdgcn_rsqf(d2);   // ~1/(D+1e-6), ~1/|V+eps|
            float OqP = fmaf(dx, p.x, fmaf(dy, p.y, fmaf(dz, p.z, cP)));
            float OPP = fmaf(p.x, vpx[t], fmaf(p.y, vpy[t], p.z * vpz[t]));
            float Q12 = a.w * vq[t];
            float sf  = fmaf(invD, wd, p.w + vaj[t]);
            float invD2 = invD * invD;
            float invD4 = invD2 * invD2;
            float invD5 = invD4 * invD;
            float invD6 = invD4 * invD2;
            float E = fmaf(Q12 * invD, sf,
                      fmaf(OqP, invD5, OPP * invD6));
            es = fmaf(m[r][t], E, es);
        }
        acc += (double)es;
    }

    // ---- wave shuffle reduce + 8-entry LDS combine ----
#pragma unroll
    for (int s = 32; s > 0; s >>= 1)
        acc += __shfl_xor(acc, s, 64);

    __shared__ double wsum[THREADS / 64];
    const int lane = tid & 63;
    const int wid  = tid >> 6;
    if (lane == 0) wsum[wid] = acc;
    __syncthreads();
    if (tid == 0) {
        double bsum = 0.0;
#pragma unroll
        for (int w = 0; w < THREADS / 64; ++w) bsum += wsum[w];
        partials[blockIdx.x] = bsum;
    }
}

// --- Kernel C: final reduction + scale + NaN guard ------------------------
__global__ void finalize(const double* __restrict__ partials, int n,
                         float* __restrict__ out) {
    __shared__ double sdata[256];
    double a = 0.0;
    for (int i = threadIdx.x; i < n; i += 256) a += partials[i];
    sdata[threadIdx.x] = a;
    __syncthreads();
#pragma unroll
    for (int s = 128; s > 0; s >>= 1) {
        if (threadIdx.x < s) sdata[threadIdx.x] += sdata[threadIdx.x + s];
        __syncthreads();
    }
    if (threadIdx.x == 0) {
        double tot = sdata[0] * (double)CONVF * 0.5;
        float f = (float)tot;
        out[0] = isnan(f) ? 1e-6f : f;
    }
}

extern "C" void kernel_launch(void* const* d_in, const int* in_sizes, int n_in,
                              void* d_out, int out_size, void* d_ws, size_t ws_size,
                              hipStream_t stream) {
    const float* X    = (const float*)d_in[0];
    const float* embs = (const float*)d_in[1];
    const float* qs   = (const float*)d_in[2];
    const float* Ps   = (const float*)d_in[3];
    const float* mask = (const float*)d_in[4];
    const float* sfw  = (const float*)d_in[5];
    float* out = (float*)d_out;

    // workspace: [ partials double[NBLOCKS] | pkI float4[B*N*2] | pkT float[8*NQUADS*4] ]
    double* partials = (double*)d_ws;
    float4* pkI = (float4*)(partials + NBLOCKS);
    float*  pkT = (float*)(pkI + BATCH * NPTS * 2);

    pack_points<<<(BATCH * NPTS + 255) / 256, 256, 0, stream>>>(X, embs, qs, Ps, sfw,
                                                                pkI, pkT);
    pair_energy<<<NBLOCKS, THREADS, 0, stream>>>(pkI, (const f4v*)pkT,
                                                 (const f4v*)mask, sfw, partials);
    finalize<<<1, 256, 0, stream>>>(partials, NBLOCKS, out);
}